// Round 1
// baseline (237.960 us; speedup 1.0000x reference)
//
#include <hip/hip_runtime.h>
#include <hip/hip_bf16.h>
#include <stdint.h>

#define B_ 8
#define N_ 1024
#define C_ 1024
#define H_ 16

static constexpr float SCALE = 0.125f;            // 64^-0.5
static constexpr float LOG2E = 1.4426950408889634f;

typedef __attribute__((ext_vector_type(4))) float f32x4;
typedef __attribute__((ext_vector_type(8))) short s16x8;

__device__ __forceinline__ ushort f2bf(float f) {
    union { float f; uint32_t u; } c; c.f = f;
    uint32_t u = c.u;
    return (ushort)((u + 0x7fffu + ((u >> 16) & 1u)) >> 16);
}

__device__ __forceinline__ void gload_lds16(const void* g, void* l) {
    __builtin_amdgcn_global_load_lds(
        (const __attribute__((address_space(1))) void*)g,
        (__attribute__((address_space(3))) void*)l,
        16, 0, 0);
}

// ---------------- fp32 -> bf16 conversion ----------------
__global__ __launch_bounds__(256) void cvt_f32_bf16(const float* __restrict__ in,
                                                    ushort* __restrict__ out, int n4) {
    int i = blockIdx.x * 256 + threadIdx.x;
    if (i >= n4) return;
    float4 v = ((const float4*)in)[i];
    ushort4 o = make_ushort4(f2bf(v.x), f2bf(v.y), f2bf(v.z), f2bf(v.w));
    ((ushort4*)out)[i] = o;
}

// ---------------- C = A * B^T (both row-major [.,K] bf16), optional bias / bf16 out ----------------
// 128x128 tile, BK=64, 4 waves in 2x2, each wave 64x64 (4x4 frags of 16x16x32 MFMA).
// LDS staged via global_load_lds w=16 with 16B-chunk XOR swizzle (c ^ (row&7)), pre-swizzled global src.
template<int OUT_BF16>
__global__ __launch_bounds__(256) void gemm_bt(const ushort* __restrict__ A,
                                               const ushort* __restrict__ Bw,
                                               void* __restrict__ Cout,
                                               const float* __restrict__ bias,
                                               int M, int Nout, int K) {
    __shared__ ushort Asm[128 * 64];
    __shared__ ushort Bsm[128 * 64];
    const int t = threadIdx.x;
    const int l = t & 63, w = t >> 6;
    const int lq = l & 15, lg = l >> 4;
    const int trow = blockIdx.y * 128, tcol = blockIdx.x * 128;
    const int wrow = (w >> 1) * 64, wcol = (w & 1) * 64;

    f32x4 acc[4][4] = {};

    // staging: chunk p = i*256 + t, row = p>>3, src col-chunk = (p&7) ^ (row&7)
    const int srow0 = t >> 3;
    const int sc8 = (((t & 7) ^ (srow0 & 7)) * 8);
    const size_t abase = (size_t)(trow + srow0) * K + sc8;
    const size_t bbase = (size_t)(tcol + srow0) * K + sc8;

    for (int k0 = 0; k0 < K; k0 += 64) {
#pragma unroll
        for (int i = 0; i < 4; ++i) {
            gload_lds16(A + abase + (size_t)i * 32 * K + k0, &Asm[(i * 256 + w * 64) * 8]);
            gload_lds16(Bw + bbase + (size_t)i * 32 * K + k0, &Bsm[(i * 256 + w * 64) * 8]);
        }
        __syncthreads();
#pragma unroll
        for (int kk = 0; kk < 2; ++kk) {
            s16x8 af[4], bf[4];
#pragma unroll
            for (int m = 0; m < 4; ++m) {
                int row = wrow + m * 16 + lq;
                int ch = (kk * 4 + lg) ^ (row & 7);
                af[m] = *(const s16x8*)&Asm[row * 64 + ch * 8];
            }
#pragma unroll
            for (int n = 0; n < 4; ++n) {
                int row = wcol + n * 16 + lq;
                int ch = (kk * 4 + lg) ^ (row & 7);
                bf[n] = *(const s16x8*)&Bsm[row * 64 + ch * 8];
            }
#pragma unroll
            for (int m = 0; m < 4; ++m)
#pragma unroll
                for (int n = 0; n < 4; ++n)
                    acc[m][n] = __builtin_amdgcn_mfma_f32_16x16x32_bf16(af[m], bf[n], acc[m][n], 0, 0, 0);
        }
        __syncthreads();
    }

#pragma unroll
    for (int m = 0; m < 4; ++m)
#pragma unroll
        for (int n = 0; n < 4; ++n)
#pragma unroll
            for (int r = 0; r < 4; ++r) {
                int row = trow + wrow + m * 16 + lg * 4 + r;
                int col = tcol + wcol + n * 16 + lq;
                if (OUT_BF16) {
                    ((ushort*)Cout)[(size_t)row * Nout + col] = f2bf(acc[m][n][r]);
                } else {
                    ((float*)Cout)[(size_t)row * Nout + col] = acc[m][n][r] + bias[col];
                }
            }
}

// ---------------- fused flash attention ----------------
// grid: (N/64 q-tiles, B*H). 4 waves x 16 q-rows. KV tiles of 32 keys staged in LDS.
// Swapped QK^T: mfma(A=K, B=Q) -> lane owns scores of query (l&15); softmax fully in-register;
// P staged through padded per-wave LDS (16x40) to form the MFMA A-layout for PV.
__global__ __launch_bounds__(256) void attn_fwd(const ushort* __restrict__ qkv,
                                                ushort* __restrict__ attn_out) {
    __shared__ ushort Klds[32 * 64];
    __shared__ ushort Vlds[32 * 64];
    __shared__ ushort Plds[4][16 * 40];

    const int t = threadIdx.x, l = t & 63, w = t >> 6;
    const int lq = l & 15, lg = l >> 4;
    const int bh = blockIdx.y, b = bh >> 4, h = bh & 15;
    const int qt = blockIdx.x;

    // Q fragments (held in regs for the whole block)
    const int qrow = qt * 64 + w * 16 + lq;
    const size_t qoff = ((size_t)(b * N_ + qrow) * 3) * C_ + h * 64;
    const s16x8 qf0 = *(const s16x8*)&qkv[qoff + lg * 8];
    const s16x8 qf1 = *(const s16x8*)&qkv[qoff + 32 + lg * 8];

    float m_run = -1e30f, l_run = 0.f;
    f32x4 o[4] = {};

    // K/V staging addresses: chunk t covers (key=t>>3, c=t&7), source chunk pre-swizzled
    const int skey = t >> 3;
    const int sc8 = ((t & 7) ^ (skey & 7)) * 8;
    const size_t kgbase = ((size_t)(b * N_ + skey) * 3 + 1) * C_ + h * 64 + sc8;
    const size_t vgbase = kgbase + C_;

    for (int kt = 0; kt < N_ / 32; ++kt) {
        const size_t off = (size_t)kt * 32 * 3 * C_;
        gload_lds16(qkv + kgbase + off, &Klds[w * 64 * 8]);
        gload_lds16(qkv + vgbase + off, &Vlds[w * 64 * 8]);
        __syncthreads();

        // S^T tiles: s0 = keys [0..15], s1 = keys [16..31] of this KV tile
        f32x4 s0, s1;
        {
            int key = lq;
            s16x8 kf0 = *(const s16x8*)&Klds[key * 64 + ((lg ^ (key & 7)) * 8)];
            s16x8 kf1 = *(const s16x8*)&Klds[key * 64 + (((4 + lg) ^ (key & 7)) * 8)];
            f32x4 z = {};
            z  = __builtin_amdgcn_mfma_f32_16x16x32_bf16(kf0, qf0, z, 0, 0, 0);
            s0 = __builtin_amdgcn_mfma_f32_16x16x32_bf16(kf1, qf1, z, 0, 0, 0);
        }
        {
            int key = 16 + lq;
            s16x8 kf0 = *(const s16x8*)&Klds[key * 64 + ((lg ^ (key & 7)) * 8)];
            s16x8 kf1 = *(const s16x8*)&Klds[key * 64 + (((4 + lg) ^ (key & 7)) * 8)];
            f32x4 z = {};
            z  = __builtin_amdgcn_mfma_f32_16x16x32_bf16(kf0, qf0, z, 0, 0, 0);
            s1 = __builtin_amdgcn_mfma_f32_16x16x32_bf16(kf1, qf1, z, 0, 0, 0);
        }

        // online softmax for query q = lq (values replicated across the 4 lane-groups)
        float sv[8];
#pragma unroll
        for (int i = 0; i < 4; ++i) { sv[i] = s0[i] * SCALE; sv[4 + i] = s1[i] * SCALE; }
        float mx = sv[0];
#pragma unroll
        for (int i = 1; i < 8; ++i) mx = fmaxf(mx, sv[i]);
        mx = fmaxf(mx, __shfl_xor(mx, 16));
        mx = fmaxf(mx, __shfl_xor(mx, 32));
        float m_new = fmaxf(m_run, mx);
        float fs = exp2f((m_run - m_new) * LOG2E);
        float psum = 0.f;
        ushort pb[8];
#pragma unroll
        for (int i = 0; i < 8; ++i) {
            float p = exp2f((sv[i] - m_new) * LOG2E);
            psum += p;
            pb[i] = f2bf(p);
        }
        psum += __shfl_xor(psum, 16);
        psum += __shfl_xor(psum, 32);
        l_run = l_run * fs + psum;
        m_run = m_new;

        // stage P (A-layout) through per-wave padded LDS: row q=lq, k = lg*4+r (lo) / 16+lg*4+r (hi)
        uint64_t plo = (uint64_t)pb[0] | ((uint64_t)pb[1] << 16) | ((uint64_t)pb[2] << 32) | ((uint64_t)pb[3] << 48);
        uint64_t phi = (uint64_t)pb[4] | ((uint64_t)pb[5] << 16) | ((uint64_t)pb[6] << 32) | ((uint64_t)pb[7] << 48);
        *(uint64_t*)&Plds[w][lq * 40 + lg * 4] = plo;
        *(uint64_t*)&Plds[w][lq * 40 + 16 + lg * 4] = phi;

        // rescale O (O's lane layout: q = lg*4+r, d = ds*16+lq) — fetch per-query factors
        float f0 = __shfl(fs, lg * 4 + 0);
        float f1 = __shfl(fs, lg * 4 + 1);
        float f2 = __shfl(fs, lg * 4 + 2);
        float f3 = __shfl(fs, lg * 4 + 3);
#pragma unroll
        for (int ds = 0; ds < 4; ++ds) {
            o[ds][0] *= f0; o[ds][1] *= f1; o[ds][2] *= f2; o[ds][3] *= f3;
        }

        // PV: A = P[16q x 32k] from Plds, B = V[32k x 16d-slice] via swizzled scalar LDS reads
        s16x8 pf = *(const s16x8*)&Plds[w][lq * 40 + lg * 8];
#pragma unroll
        for (int ds = 0; ds < 4; ++ds) {
            s16x8 vf;
#pragma unroll
            for (int j = 0; j < 8; ++j) {
                int k = lg * 8 + j;
                int d = ds * 16 + lq;
                vf[j] = (short)Vlds[k * 64 + (((d >> 3) ^ (k & 7)) * 8) + (d & 7)];
            }
            o[ds] = __builtin_amdgcn_mfma_f32_16x16x32_bf16(pf, vf, o[ds], 0, 0, 0);
        }
        __syncthreads();
    }

    // epilogue: normalize and store [b, n, h*64+d]
#pragma unroll
    for (int r = 0; r < 4; ++r) {
        float rl = 1.f / __shfl(l_run, lg * 4 + r);
        int orow = qt * 64 + w * 16 + lg * 4 + r;
        size_t base = (size_t)(b * N_ + orow) * C_ + h * 64 + lq;
#pragma unroll
        for (int ds = 0; ds < 4; ++ds)
            attn_out[base + ds * 16] = f2bf(o[ds][r] * rl);
    }
}

extern "C" void kernel_launch(void* const* d_in, const int* in_sizes, int n_in,
                              void* d_out, int out_size, void* d_ws, size_t ws_size,
                              hipStream_t stream) {
    const float* x      = (const float*)d_in[0];
    const float* qkv_w  = (const float*)d_in[1];
    const float* proj_w = (const float*)d_in[2];
    const float* proj_b = (const float*)d_in[3];
    float* out = (float*)d_out;

    // workspace layout (bf16 as ushort)
    ushort* ws    = (ushort*)d_ws;
    ushort* xb    = ws;                                   //  8192*1024
    ushort* wqkv  = xb + (size_t)8192 * 1024;             //  3072*1024
    ushort* wproj = wqkv + (size_t)3072 * 1024;           //  1024*1024
    ushort* qkv   = wproj + (size_t)1024 * 1024;          //  8192*3072
    ushort* attn  = qkv + (size_t)8192 * 3072;            //  8192*1024

    cvt_f32_bf16<<<8192, 256, 0, stream>>>(x, xb, 2097152);
    cvt_f32_bf16<<<3072, 256, 0, stream>>>(qkv_w, wqkv, 786432);
    cvt_f32_bf16<<<1024, 256, 0, stream>>>(proj_w, wproj, 262144);

    gemm_bt<1><<<dim3(24, 64), 256, 0, stream>>>(xb, wqkv, (void*)qkv, nullptr, 8192, 3072, 1024);

    attn_fwd<<<dim3(16, 128), 256, 0, stream>>>(qkv, attn);

    gemm_bt<0><<<dim3(8, 64), 256, 0, stream>>>(attn, wproj, (void*)out, proj_b, 8192, 1024, 1024);
}

// Round 4
// 189.696 us; speedup vs baseline: 1.2544x; 1.2544x over previous
//
#include <hip/hip_runtime.h>
#include <hip/hip_bf16.h>
#include <stdint.h>

#define B_ 8
#define N_ 1024
#define C_ 1024
#define H_ 16

static constexpr float SCALE = 0.125f;            // 64^-0.5
static constexpr float LOG2E = 1.4426950408889634f;
static constexpr float SL    = SCALE * LOG2E;     // fold scale into exp2 arg

typedef __attribute__((ext_vector_type(4))) float f32x4;
typedef __attribute__((ext_vector_type(8))) short s16x8;

__device__ __forceinline__ ushort f2bf(float f) {
    union { float f; uint32_t u; } c; c.f = f;
    uint32_t u = c.u;
    return (ushort)((u + 0x7fffu + ((u >> 16) & 1u)) >> 16);
}

__device__ __forceinline__ void gload_lds16(const void* g, void* l) {
    __builtin_amdgcn_global_load_lds(
        (const __attribute__((address_space(1))) void*)g,
        (__attribute__((address_space(3))) void*)l,
        16, 0, 0);
}

// ---------------- fp32 -> bf16 conversion ----------------
__global__ __launch_bounds__(256) void cvt_f32_bf16(const float* __restrict__ in,
                                                    ushort* __restrict__ out, int n4) {
    int i = blockIdx.x * 256 + threadIdx.x;
    if (i >= n4) return;
    float4 v = ((const float4*)in)[i];
    ushort4 o = make_ushort4(f2bf(v.x), f2bf(v.y), f2bf(v.z), f2bf(v.w));
    ((ushort4*)out)[i] = o;
}

// ---------------- C = A * B^T (both row-major [.,K] bf16), optional bias / bf16 out ----------------
template<int OUT_BF16>
__global__ __launch_bounds__(256) void gemm_bt(const ushort* __restrict__ A,
                                               const ushort* __restrict__ Bw,
                                               void* __restrict__ Cout,
                                               const float* __restrict__ bias,
                                               int M, int Nout, int K) {
    __shared__ ushort Asm[128 * 64];
    __shared__ ushort Bsm[128 * 64];
    const int t = threadIdx.x;
    const int l = t & 63, w = t >> 6;
    const int lq = l & 15, lg = l >> 4;
    const int trow = blockIdx.y * 128, tcol = blockIdx.x * 128;
    const int wrow = (w >> 1) * 64, wcol = (w & 1) * 64;

    f32x4 acc[4][4] = {};

    const int srow0 = t >> 3;
    const int sc8 = (((t & 7) ^ (srow0 & 7)) * 8);
    const size_t abase = (size_t)(trow + srow0) * K + sc8;
    const size_t bbase = (size_t)(tcol + srow0) * K + sc8;

    for (int k0 = 0; k0 < K; k0 += 64) {
#pragma unroll
        for (int i = 0; i < 4; ++i) {
            gload_lds16(A + abase + (size_t)i * 32 * K + k0, &Asm[(i * 256 + w * 64) * 8]);
            gload_lds16(Bw + bbase + (size_t)i * 32 * K + k0, &Bsm[(i * 256 + w * 64) * 8]);
        }
        __syncthreads();
#pragma unroll
        for (int kk = 0; kk < 2; ++kk) {
            s16x8 af[4], bf[4];
#pragma unroll
            for (int m = 0; m < 4; ++m) {
                int row = wrow + m * 16 + lq;
                int ch = (kk * 4 + lg) ^ (row & 7);
                af[m] = *(const s16x8*)&Asm[row * 64 + ch * 8];
            }
#pragma unroll
            for (int n = 0; n < 4; ++n) {
                int row = wcol + n * 16 + lq;
                int ch = (kk * 4 + lg) ^ (row & 7);
                bf[n] = *(const s16x8*)&Bsm[row * 64 + ch * 8];
            }
#pragma unroll
            for (int m = 0; m < 4; ++m)
#pragma unroll
                for (int n = 0; n < 4; ++n)
                    acc[m][n] = __builtin_amdgcn_mfma_f32_16x16x32_bf16(af[m], bf[n], acc[m][n], 0, 0, 0);
        }
        __syncthreads();
    }

#pragma unroll
    for (int m = 0; m < 4; ++m)
#pragma unroll
        for (int n = 0; n < 4; ++n)
#pragma unroll
            for (int r = 0; r < 4; ++r) {
                int row = trow + wrow + m * 16 + lg * 4 + r;
                int col = tcol + wcol + n * 16 + lq;
                if (OUT_BF16) {
                    ((ushort*)Cout)[(size_t)row * Nout + col] = f2bf(acc[m][n][r]);
                } else {
                    ((float*)Cout)[(size_t)row * Nout + col] = acc[m][n][r] + bias[col];
                }
            }
}

// ---------------- fused flash attention ----------------
// grid 2048 blocks (XCD-swizzled: 16 q-tiles of one (b,h) share an XCD L2).
// 4 waves x 16 q-rows each. KVBLK=64.
// K: global_load_lds direct, [64][64] with 16B-chunk XOR swizzle (verified r1/r2-audit).
// V: reg-staged, TRANSPOSED + KEY-PERMUTED into Vt[64d][64k] via scalar ds_write_b16
//    (verified primitives only), XOR swizzle chunk ^= (d ^ d>>3)&7 -> <=2-way both sides.
//    Key permutation key(c)= (2*(c>>5)+((c&7)>>2))*16 + ((c>>3)&3)*4 + (c&3) makes the
//    PV A-fragment lane-local in the QK^T score registers: NO P LDS round-trip.
// Swapped QK^T (mfma(K,Q)): lane owns scores of query q=l&15; softmax in-register;
// defer-max rescale (T13, THR=8 in exp2 units).
__global__ __launch_bounds__(256) void attn_fwd(const ushort* __restrict__ qkv,
                                                ushort* __restrict__ attn_out) {
    __shared__ ushort Klds[64 * 64];
    __shared__ ushort Vt[64 * 64];     // [d][key-slot], swizzled

    const int t = threadIdx.x, l = t & 63, w = t >> 6;
    const int lq = l & 15, lg = l >> 4;

    // XCD-aware swizzle: serial = bx + 16*by; xcd = serial&7 gets 16 consecutive bh's
    const int serial = blockIdx.x + 16 * blockIdx.y;
    const int logical = (serial & 7) * 256 + (serial >> 3);
    const int qt = logical & 15;
    const int bh = logical >> 4;
    const int b = bh >> 4, h = bh & 15;

    // Q fragments held in regs for the whole block
    const int qrow = qt * 64 + w * 16 + lq;
    const size_t qoff = ((size_t)(b * N_ + qrow) * 3) * C_ + h * 64;
    const s16x8 qf0 = *(const s16x8*)&qkv[qoff + lg * 8];
    const s16x8 qf1 = *(const s16x8*)&qkv[qoff + 32 + lg * 8];

    float m_run = -1e30f, l_run = 0.f;
    f32x4 o[4] = {};

    // K staging: chunk p = i*256 + t -> (row=p>>3, c=p&7), source chunk pre-swizzled
    const int srow0 = t >> 3;
    const int sc8 = ((t & 7) ^ (srow0 & 7)) * 8;
    const size_t kgbase = ((size_t)(b * N_ + srow0) * 3 + 1) * C_ + h * 64 + sc8;

    // V staging precompute: thread owns key=srow0 (and +32), d-chunk vdc = t&7.
    // column c(key) in permuted Vt; write idx = vdc*512 + j*64 + ((x ^ j)*8) + (c&7)
    const int vdc = t & 7;
    const int g_lo = srow0 >> 4, g_hi = (srow0 + 32) >> 4;
    const int c_lo = (g_lo >> 1) * 32 + ((srow0 >> 2) & 3) * 8 + (g_lo & 1) * 4 + (srow0 & 3);
    const int c_hi = (g_hi >> 1) * 32 + ((srow0 >> 2) & 3) * 8 + (g_hi & 1) * 4 + (srow0 & 3);
    const int base_lo = vdc * 512 + (c_lo & 7), x_lo = (c_lo >> 3) ^ vdc;
    const int base_hi = vdc * 512 + (c_hi & 7), x_hi = (c_hi >> 3) ^ vdc;
    const size_t vgbase = ((size_t)(b * N_ + srow0) * 3 + 2) * C_ + h * 64 + vdc * 8;

    // PV read swizzle base: d = ds*16+lq -> swz = (lq&7) ^ (lq>>3) ^ (ds*2)
    const int swzbase = (lq & 7) ^ (lq >> 3);

    for (int kt = 0; kt < N_ / 64; ++kt) {
        const size_t off = (size_t)kt * 64 * 3 * C_;
        // K -> LDS direct (rows 0..31 then 32..63)
        gload_lds16(qkv + kgbase + off, &Klds[(w * 64) * 8]);
        gload_lds16(qkv + kgbase + off + (size_t)32 * 3 * C_, &Klds[(256 + w * 64) * 8]);
        // V -> regs -> transposed/permuted Vt
        float4 va = *(const float4*)&qkv[vgbase + off];
        float4 vb = *(const float4*)&qkv[vgbase + off + (size_t)32 * 3 * C_];
        const ushort* pa = (const ushort*)&va;
        const ushort* pb = (const ushort*)&vb;
#pragma unroll
        for (int j = 0; j < 8; ++j) {
            Vt[base_lo + j * 64 + ((x_lo ^ j) * 8)] = pa[j];
            Vt[base_hi + j * 64 + ((x_hi ^ j) * 8)] = pb[j];
        }
        __syncthreads();

        // QK^T: 4 key-groups of 16, S^T[key][q] in s[g]
        f32x4 s[4];
#pragma unroll
        for (int g = 0; g < 4; ++g) {
            int key = g * 16 + lq;
            const s16x8 kf0 = *(const s16x8*)&Klds[key * 64 + ((lg ^ (key & 7)) * 8)];
            const s16x8 kf1 = *(const s16x8*)&Klds[key * 64 + (((4 + lg) ^ (key & 7)) * 8)];
            f32x4 z = {};
            z    = __builtin_amdgcn_mfma_f32_16x16x32_bf16(kf0, qf0, z, 0, 0, 0);
            s[g] = __builtin_amdgcn_mfma_f32_16x16x32_bf16(kf1, qf1, z, 0, 0, 0);
        }

        // online softmax (query q=lq; lane holds keys g*16+lg*4+i)
        float mx = s[0][0];
#pragma unroll
        for (int g = 0; g < 4; ++g)
#pragma unroll
            for (int i = 0; i < 4; ++i) mx = fmaxf(mx, s[g][i]);
        mx = fmaxf(mx, __shfl_xor(mx, 16));
        mx = fmaxf(mx, __shfl_xor(mx, 32));

        float m_new = fmaxf(m_run, mx);
        float fs;
        if ((m_new - m_run) * SL <= 8.0f) { m_new = m_run; fs = 1.0f; }  // defer-max
        else fs = exp2f((m_run - m_new) * SL);
        m_run = m_new;
        const float mS = m_new * SL;

        float pv[4][4];
        float psum = 0.f;
#pragma unroll
        for (int g = 0; g < 4; ++g) {
            float p0 = exp2f(__builtin_fmaf(s[g][0], SL, -mS));
            float p1 = exp2f(__builtin_fmaf(s[g][1], SL, -mS));
            float p2 = exp2f(__builtin_fmaf(s[g][2], SL, -mS));
            float p3 = exp2f(__builtin_fmaf(s[g][3], SL, -mS));
            psum += (p0 + p1) + (p2 + p3);
            pv[g][0] = p0; pv[g][1] = p1; pv[g][2] = p2; pv[g][3] = p3;
        }
        psum += __shfl_xor(psum, 16);
        psum += __shfl_xor(psum, 32);
        l_run = l_run * fs + psum;

        // rescale O only when some query's max grew (o row q = lg*4+r, col d = ds*16+lq)
        if (__any(fs != 1.0f)) {
            float f0 = __shfl(fs, lg * 4 + 0);
            float f1 = __shfl(fs, lg * 4 + 1);
            float f2 = __shfl(fs, lg * 4 + 2);
            float f3 = __shfl(fs, lg * 4 + 3);
#pragma unroll
            for (int ds = 0; ds < 4; ++ds) {
                o[ds][0] *= f0; o[ds][1] *= f1; o[ds][2] *= f2; o[ds][3] *= f3;
            }
        }

        // PV: pf is lane-local (key permutation matches Vt column order)
#pragma unroll
        for (int kb = 0; kb < 2; ++kb) {
            s16x8 pf;
#pragma unroll
            for (int i = 0; i < 4; ++i) {
                pf[i]     = (short)f2bf(pv[2 * kb][i]);
                pf[4 + i] = (short)f2bf(pv[2 * kb + 1][i]);
            }
#pragma unroll
            for (int ds = 0; ds < 4; ++ds) {
                const s16x8 vf = *(const s16x8*)
                    &Vt[(ds * 16 + lq) * 64 + (((kb * 4 + lg) ^ swzbase ^ (ds * 2)) * 8)];
                o[ds] = __builtin_amdgcn_mfma_f32_16x16x32_bf16(pf, vf, o[ds], 0, 0, 0);
            }
        }
        __syncthreads();
    }

    // epilogue: normalize and store [b, n, h*64+d]
#pragma unroll
    for (int r = 0; r < 4; ++r) {
        float rl = 1.f / __shfl(l_run, lg * 4 + r);
        int orow = qt * 64 + w * 16 + lg * 4 + r;
        size_t base = (size_t)(b * N_ + orow) * C_ + h * 64 + lq;
#pragma unroll
        for (int ds = 0; ds < 4; ++ds)
            attn_out[base + ds * 16] = f2bf(o[ds][r] * rl);
    }
}

extern "C" void kernel_launch(void* const* d_in, const int* in_sizes, int n_in,
                              void* d_out, int out_size, void* d_ws, size_t ws_size,
                              hipStream_t stream) {
    const float* x      = (const float*)d_in[0];
    const float* qkv_w  = (const float*)d_in[1];
    const float* proj_w = (const float*)d_in[2];
    const float* proj_b = (const float*)d_in[3];
    float* out = (float*)d_out;

    ushort* ws    = (ushort*)d_ws;
    ushort* xb    = ws;                                   //  8192*1024
    ushort* wqkv  = xb + (size_t)8192 * 1024;             //  3072*1024
    ushort* wproj = wqkv + (size_t)3072 * 1024;           //  1024*1024
    ushort* qkv   = wproj + (size_t)1024 * 1024;          //  8192*3072
    ushort* attn  = qkv + (size_t)8192 * 3072;            //  8192*1024

    cvt_f32_bf16<<<8192, 256, 0, stream>>>(x, xb, 2097152);
    cvt_f32_bf16<<<3072, 256, 0, stream>>>(qkv_w, wqkv, 786432);
    cvt_f32_bf16<<<1024, 256, 0, stream>>>(proj_w, wproj, 262144);

    gemm_bt<1><<<dim3(24, 64), 256, 0, stream>>>(xb, wqkv, (void*)qkv, nullptr, 8192, 3072, 1024);

    attn_fwd<<<dim3(16, 128), 256, 0, stream>>>(qkv, attn);

    gemm_bt<0><<<dim3(8, 64), 256, 0, stream>>>(attn, wproj, (void*)out, proj_b, 8192, 1024, 1024);
}